// Round 10
// baseline (310.231 us; speedup 1.0000x reference)
//
#include <hip/hip_runtime.h>
#include <hip/hip_bf16.h>
#include <stdint.h>

#define B_ 1024
#define T_ 255
#define D_ 128

typedef float f32x4 __attribute__((ext_vector_type(4)));
typedef short s16x8 __attribute__((ext_vector_type(8)));
typedef unsigned u32x4 __attribute__((ext_vector_type(4)));

__device__ __forceinline__ unsigned pk2(float a, float b){
  __hip_bfloat162 h2 = __float22bfloat162_rn(make_float2(a, b));  // v_cvt_pk_bf16_f32
  union { __hip_bfloat162 h; unsigned u; } c; c.h = h2; return c.u;
}
__device__ __forceinline__ unsigned short bf1(float a){
  __hip_bfloat16 h = __float2bfloat16(a);
  union { __hip_bfloat16 h; unsigned short u; } c; c.h = h; return c.u;
}
__device__ __forceinline__ float sigm_f(float x){
  return __builtin_amdgcn_rcpf(1.f + __expf(-x));
}
__device__ __forceinline__ float tanh_f2(float x){
  return fmaf(-2.f, __builtin_amdgcn_rcpf(1.f + __expf(2.f * x)), 1.f);
}

// ---------------- Kernel 1: softmax(x_part) ; out_w = attn*x ; wx bf16 ----------
__global__ __launch_bounds__(512) void k_attn(const float* __restrict__ x,
    const float* __restrict__ Wa, float* __restrict__ out_w,
    uint2* __restrict__ wxq){
  extern __shared__ float4 xs4[];          // 8160 float4 = 130560 B
  __shared__ float wxs[256];
  __shared__ float part_s[16][128];
  __shared__ float red[128];
  __shared__ float attn_s[128];
  int tid = threadIdx.x, b = blockIdx.x;
  if (tid < T_) wxs[tid] = Wa[2 * D_ + tid];
  __syncthreads();
  const float4* xg = (const float4*)(x + (size_t)b * T_ * D_);
  float4 acc = {0.f, 0.f, 0.f, 0.f};
  for (int i = tid; i < 8160; i += 512){
    float4 v = xg[i];
    xs4[i] = v;
    float wt = wxs[i >> 5];
    acc.x += v.x * wt; acc.y += v.y * wt; acc.z += v.z * wt; acc.w += v.w * wt;
  }
  int d0 = (tid & 31) * 4, s = tid >> 5;
  *(float4*)&part_s[s][d0] = acc;
  __syncthreads();
  if (tid < 128){
    float v = 0.f;
    #pragma unroll
    for (int k = 0; k < 16; k++) v += part_s[k][tid];
    red[tid] = v; attn_s[tid] = v;
  }
  __syncthreads();
  for (int st = 64; st >= 1; st >>= 1){
    if (tid < st) red[tid] = fmaxf(red[tid], red[tid + st]);
    __syncthreads();
  }
  float mx = red[0];
  __syncthreads();
  float ev = 0.f;
  if (tid < 128){ ev = __expf(attn_s[tid] - mx); red[tid] = ev; }
  __syncthreads();
  for (int st = 64; st >= 1; st >>= 1){
    if (tid < st) red[tid] += red[tid + st];
    __syncthreads();
  }
  float sm = red[0];
  if (tid < 128) attn_s[tid] = ev / sm;
  __syncthreads();
  float4 at = *(const float4*)&attn_s[d0];
  float4* owg = (float4*)(out_w + (size_t)b * T_ * D_);
  for (int i = tid; i < 8160; i += 512){
    float4 v = xs4[i];
    float4 wv; wv.x = v.x*at.x; wv.y = v.y*at.y; wv.z = v.z*at.z; wv.w = v.w*at.w;
    owg[i] = wv;
    int t = i >> 5;
    uint2 q;
    q.x = pk2(wv.x, wv.y);
    q.y = pk2(wv.z, wv.w);
    wxq[((size_t)t * B_ + b) * 32 + (i & 31)] = q;   // [t][b][d] bf16 row-major
  }
}

// ---------------- Kernel 2: fused recurrence. 256 blocks x 4 rows x 4 waves -----
// ONE wave per SIMD (no twin-convoy). Wave w owns d-slice [32w,32w+32): 8 n-tiles
// (4 gates x 2 sub-cols), 2 cells/lane (d0=32w+l15, d1=d0+16; row lg via acc[0]).
// Holds BOTH W_hh and W_ih frags (~256 VGPR; launch_bounds(256,1) caps at 512).
// fih batched over 4 steps (M=16 full: A row l15=(ts,br)) -> G1 float4 in LDS
// (wave-local). fhh per step: h rows x4-replicated, r7-proven swizzle.
__global__ __launch_bounds__(256, 1) void k_rnn(const float* __restrict__ W_ih,
    const float* __restrict__ W_hh, const float* __restrict__ b_ih,
    const float* __restrict__ b_hh, const unsigned short* __restrict__ wxb,
    float* __restrict__ out_e){
  __shared__ char hl[2048];      // h bf16 [buf][row 256B][slot 16B], slot^=(row&1)<<2
  __shared__ float4 g1l[2048];   // 32 KB f32 G1: [m=ts*4+br][d] {i,f,g,o}
  int tid = threadIdx.x;
  int lane = tid & 63, w = tid >> 6;
  int l15 = lane & 15, lg = lane >> 4;
  int row0 = blockIdx.x << 2;
  int d0 = w * 32 + l15, d1 = d0 + 16;
  int hr = l15 >> 2;             // h row this lane reads (x4 replication)

  // weight B-fragments [kt][gate][j], k = kt*32 + lg*8 + jj ; n = g*128+32w+16j+l15
  s16x8 fih[4][4][2], fhh[4][4][2];
  float bias[4][2];
  #pragma unroll
  for (int g = 0; g < 4; g++){
    #pragma unroll
    for (int j = 0; j < 2; j++){
      int n = g * 128 + w * 32 + j * 16 + l15;
      bias[g][j] = b_ih[n] + b_hh[n];
      #pragma unroll
      for (int kt = 0; kt < 4; kt++){
        const float4* p1 = (const float4*)(W_ih + n * D_ + kt * 32 + lg * 8);
        float4 a0 = p1[0], a1 = p1[1];
        u32x4 bv;
        bv[0] = pk2(a0.x, a0.y); bv[1] = pk2(a0.z, a0.w);
        bv[2] = pk2(a1.x, a1.y); bv[3] = pk2(a1.z, a1.w);
        fih[kt][g][j] = __builtin_bit_cast(s16x8, bv);
        const float4* p2 = (const float4*)(W_hh + n * D_ + kt * 32 + lg * 8);
        float4 c0v = p2[0], c1v = p2[1];
        u32x4 cv;
        cv[0] = pk2(c0v.x, c0v.y); cv[1] = pk2(c0v.z, c0v.w);
        cv[2] = pk2(c1v.x, c1v.y); cv[3] = pk2(c1v.z, c1v.w);
        fhh[kt][g][j] = __builtin_bit_cast(s16x8, cv);
      }
    }
  }
  // h LDS addresses (r7-proven). Read slot sigma = (kt*4+lg) ^ ((hr&1)<<2).
  unsigned rd_[4];
  #pragma unroll
  for (int kt = 0; kt < 4; kt++)
    rd_[kt] = (unsigned)(hr * 256 + (((kt << 2) + lg) ^ ((hr & 1) << 2)) * 16);
  unsigned wr0 = (unsigned)(lg * 256 + ((d0 >> 3) ^ ((lg & 1) << 2)) * 16 + (d0 & 7) * 2);
  unsigned wr1 = (unsigned)(lg * 256 + ((d1 >> 3) ^ ((lg & 1) << 2)) * 16 + (d1 & 7) * 2);

  float* op = out_e + (size_t)(row0 + lg) * T_ * D_ + d0;   // d1 = op[16]
  float c0s = 0.f, c1s = 0.f;
  if (tid < 128) ((uint2*)hl)[tid] = make_uint2(0u, 0u);    // zero h buf0 (1 KB)

  // G1 float4 idx: write m=lg*4+r, d=32w+16j+l15 ; read m=TS*4+lg, d0/d1
  int gw0 = (lg * 4) * 128 + d0;          // + r*128 + j*16
  int gr0 = lg * 128 + d0;                // + TS*512 ; d1 = +16

  // fih A stream: lane reads wx[4*gp + (l15>>2)][row0 + (l15&3)][k-slice lg*8]
  const unsigned short* wpb = wxb + ((size_t)(l15 >> 2) * B_ + row0 + (l15 & 3)) * D_ + lg * 8;
  const size_t GSTRIDE = (size_t)4 * B_ * D_;               // 4 timesteps
  s16x8 AF0[4], AF1[4];
  #pragma unroll
  for (int kt = 0; kt < 4; kt++) AF0[kt] = *(const s16x8*)(wpb + kt * 32);
  #pragma unroll
  for (int kt = 0; kt < 4; kt++) AF1[kt] = *(const s16x8*)(wpb + GSTRIDE + kt * 32);
  __syncthreads();

#define BAR() do {                                                                  \
    asm volatile("s_waitcnt lgkmcnt(0)" ::: "memory");                              \
    __builtin_amdgcn_s_barrier();                                                   \
  } while (0)

  // ---- batch-fih: 32 MFMA -> f32 G1 for 4 steps -> LDS (wave-local) ----
#define FIH_BATCH(AF) do {                                                          \
    f32x4 bacc[4][2];                                                               \
    _Pragma("unroll")                                                               \
    for (int g = 0; g < 4; g++)                                                     \
      _Pragma("unroll")                                                             \
      for (int j = 0; j < 2; j++){                                                  \
        float bb = bias[g][j];                                                      \
        bacc[g][j] = (f32x4){bb, bb, bb, bb};                                       \
      }                                                                             \
    _Pragma("unroll")                                                               \
    for (int kt = 0; kt < 4; kt++)                                                  \
      _Pragma("unroll")                                                             \
      for (int g = 0; g < 4; g++)                                                   \
        _Pragma("unroll")                                                           \
        for (int j = 0; j < 2; j++)                                                 \
          bacc[g][j] = __builtin_amdgcn_mfma_f32_16x16x32_bf16(                     \
                         AF[kt], fih[kt][g][j], bacc[g][j], 0, 0, 0);               \
    _Pragma("unroll")                                                               \
    for (int r = 0; r < 4; r++)                                                     \
      _Pragma("unroll")                                                             \
      for (int j = 0; j < 2; j++)                                                   \
        g1l[gw0 + r * 128 + j * 16] = make_float4(                                  \
            bacc[0][j][r], bacc[1][j][r], bacc[2][j][r], bacc[3][j][r]);            \
  } while (0)

  // ---- one recurrence step (TS compile-time 0..3; h buf parity = TS&1) ----
#define STEP(TS) do {                                                               \
    s16x8 aa[4];                                                                    \
    _Pragma("unroll")                                                               \
    for (int kt = 0; kt < 4; kt++)                                                  \
      aa[kt] = *(const s16x8*)(hl + rd_[kt] + ((TS) & 1) * 1024);                   \
    f32x4 acc[4][2];                                                                \
    _Pragma("unroll")                                                               \
    for (int g = 0; g < 4; g++)                                                     \
      _Pragma("unroll")                                                             \
      for (int j = 0; j < 2; j++) acc[g][j] = (f32x4){0.f, 0.f, 0.f, 0.f};          \
    _Pragma("unroll")                                                               \
    for (int kt = 0; kt < 4; kt++)                                                  \
      _Pragma("unroll")                                                             \
      for (int g = 0; g < 4; g++)                                                   \
        _Pragma("unroll")                                                           \
        for (int j = 0; j < 2; j++)                                                 \
          acc[g][j] = __builtin_amdgcn_mfma_f32_16x16x32_bf16(                      \
                        aa[kt], fhh[kt][g][j], acc[g][j], 0, 0, 0);                 \
    float4 q0 = g1l[gr0 + (TS) * 512];                                              \
    float4 q1 = g1l[gr0 + (TS) * 512 + 16];                                         \
    { float gi = q0.x + acc[0][0][0], gf = q0.y + acc[1][0][0];                     \
      float gg = q0.z + acc[2][0][0], go = q0.w + acc[3][0][0];                     \
      float cn = fmaf(sigm_f(gf), c0s, sigm_f(gi) * tanh_f2(gg));                   \
      float hn = sigm_f(go) * tanh_f2(cn); c0s = cn;                                \
      op[0] = hn;                                                                   \
      *(unsigned short*)(hl + wr0 + (1 - ((TS) & 1)) * 1024) = bf1(hn); }           \
    { float gi = q1.x + acc[0][1][0], gf = q1.y + acc[1][1][0];                     \
      float gg = q1.z + acc[2][1][0], go = q1.w + acc[3][1][0];                     \
      float cn = fmaf(sigm_f(gf), c1s, sigm_f(gi) * tanh_f2(gg));                   \
      float hn = sigm_f(go) * tanh_f2(cn); c1s = cn;                                \
      op[16] = hn;                                                                  \
      *(unsigned short*)(hl + wr1 + (1 - ((TS) & 1)) * 1024) = bf1(hn); }           \
    op += D_;                                                                       \
    BAR();                                                                          \
  } while (0)

  for (int g = 0; g < 62; g += 2){
    FIH_BATCH(AF0);
    #pragma unroll
    for (int kt = 0; kt < 4; kt++)
      AF0[kt] = *(const s16x8*)(wpb + (size_t)(g + 2) * GSTRIDE + kt * 32);
    STEP(0); STEP(1); STEP(2); STEP(3);
    FIH_BATCH(AF1);
    #pragma unroll
    for (int kt = 0; kt < 4; kt++)
      AF1[kt] = *(const s16x8*)(wpb + (size_t)(g + 3) * GSTRIDE + kt * 32);
    STEP(0); STEP(1); STEP(2); STEP(3);
  }
  FIH_BATCH(AF0);                         // group 62: t = 248..251
  STEP(0); STEP(1); STEP(2); STEP(3);
  FIH_BATCH(AF1);                         // group 63: t = 252..254 (+zero pad)
  STEP(0); STEP(1); STEP(2);
#undef FIH_BATCH
#undef STEP
#undef BAR
}

extern "C" void kernel_launch(void* const* d_in, const int* in_sizes, int n_in,
                              void* d_out, int out_size, void* d_ws, size_t ws_size,
                              hipStream_t stream) {
  (void)in_sizes; (void)n_in; (void)out_size;
  const float* x    = (const float*)d_in[0];
  const float* Wa   = (const float*)d_in[1];
  // d_in[2] = ba : dead (softmax shift invariance); Wh/Wc parts of Wa also dead
  const float* W_ih = (const float*)d_in[3];
  const float* W_hh = (const float*)d_in[4];
  const float* b_ih = (const float*)d_in[5];
  const float* b_hh = (const float*)d_in[6];
  float* out_w = (float*)d_out;
  float* out_e = out_w + (size_t)B_ * T_ * D_;
  unsigned short* wxb = (unsigned short*)d_ws;   // [t][b][d] bf16; T+1 slots
  size_t need = (size_t)(T_ + 1) * B_ * D_ * 2;  // 67.1 MB (t=255 pad, zeroed)
  if (ws_size < need) return;

  // zero the t=255 pad slot (prefetched by the last group, rows never read)
  hipMemsetAsync((char*)d_ws + (size_t)T_ * B_ * D_ * 2, 0, (size_t)B_ * D_ * 2, stream);
  k_attn<<<B_, 512, 130560, stream>>>(x, Wa, out_w, (uint2*)wxb);
  k_rnn <<<256, 256, 0, stream>>>(W_ih, W_hh, b_ih, b_hh, wxb, out_e);
}

// Round 11
// 306.048 us; speedup vs baseline: 1.0137x; 1.0137x over previous
//
#include <hip/hip_runtime.h>
#include <hip/hip_bf16.h>
#include <stdint.h>

#define B_ 1024
#define T_ 255
#define D_ 128

typedef float f32x4 __attribute__((ext_vector_type(4)));
typedef short s16x8 __attribute__((ext_vector_type(8)));
typedef unsigned u32x4 __attribute__((ext_vector_type(4)));

__device__ __forceinline__ unsigned pk2(float a, float b){
  __hip_bfloat162 h2 = __float22bfloat162_rn(make_float2(a, b));  // v_cvt_pk_bf16_f32
  union { __hip_bfloat162 h; unsigned u; } c; c.h = h2; return c.u;
}
__device__ __forceinline__ unsigned short bf1(float a){
  __hip_bfloat16 h = __float2bfloat16(a);
  union { __hip_bfloat16 h; unsigned short u; } c; c.h = h; return c.u;
}
// gates arrive pre-scaled by log2e (2*log2e for the g gate): raw v_exp (= 2^x)
__device__ __forceinline__ float sg(float x){       // sigmoid(orig), x = log2e*orig
  return __builtin_amdgcn_rcpf(1.f + __builtin_amdgcn_exp2f(-x));
}
__device__ __forceinline__ float tg(float x){       // tanh(orig), x = 2*log2e*orig
  return fmaf(-2.f, __builtin_amdgcn_rcpf(1.f + __builtin_amdgcn_exp2f(x)), 1.f);
}
__device__ __forceinline__ float tc_(float c){      // tanh(c), c unscaled
  return fmaf(-2.f, __builtin_amdgcn_rcpf(1.f + __builtin_amdgcn_exp2f(c * 2.88539008f)), 1.f);
}

// ---------------- fully fused: softmax + out_w + G1 + recurrence -----------------
// 256 blocks x 4 rows x 512 thr (8 waves, 2/SIMD — r7-proven step core).
// Prologue: x_part + softmax -> attn_own (1 reg/thread). Per step: wx[t+8] built
// on the fly (out_w store + bf16 into 12-deep LDS ring); FIH(g) reads A-frags from
// the ring (depth 12 => FIH-read slots disjoint from in-flight step writes).
__global__ __launch_bounds__(512, 2) void k_fused(const float* __restrict__ x,
    const float* __restrict__ Wa, const float* __restrict__ W_ih,
    const float* __restrict__ W_hh, const float* __restrict__ b_ih,
    const float* __restrict__ b_hh, float* __restrict__ out_w,
    float* __restrict__ out_e){
  __shared__ char hl[2048];      // h bf16 [buf][row 256B][slot 16B], slot^=(row&1)<<2
  __shared__ float4 g1l[2048];   // 32 KB f32 G1: [m=ts*4+br][d] {i,f,g,o} (scaled)
  __shared__ char ring[12672];   // wx bf16 ring: 12 slots x 1056 B (h-style swizzle)
  __shared__ float wxs[256];     // Wx attention weights
  __shared__ float rbuf[512];    // softmax reduction scratch

  int tid = threadIdx.x;
  int lane = tid & 63, w = tid >> 6;
  int l15 = lane & 15, lg = lane >> 4;
  int row0 = blockIdx.x << 2;
  int d = w * 16 + l15;
  int hr = l15 >> 2;             // h row this lane reads (x4 replication)
  int ts = l15 >> 2, br = l15 & 3;   // FIH A row decode (timestep-slot, batch-row)

  // weight B-fragments [kt][gate], k = kt*32 + lg*8 + j ; scaled by log2e per gate
  const float SC0 = 1.44269504f, SC2 = 2.88539008f;
  s16x8 fih[4][4], fhh[4][4];
  float biasS[4];
  #pragma unroll
  for (int g = 0; g < 4; g++){
    float sc = (g == 2) ? SC2 : SC0;
    int n = g * 128 + d;
    biasS[g] = (b_ih[n] + b_hh[n]) * sc;
    #pragma unroll
    for (int kt = 0; kt < 4; kt++){
      const float4* p1 = (const float4*)(W_ih + n * D_ + kt * 32 + lg * 8);
      float4 a0 = p1[0], a1 = p1[1];
      u32x4 bv;
      bv[0] = pk2(a0.x * sc, a0.y * sc); bv[1] = pk2(a0.z * sc, a0.w * sc);
      bv[2] = pk2(a1.x * sc, a1.y * sc); bv[3] = pk2(a1.z * sc, a1.w * sc);
      fih[kt][g] = __builtin_bit_cast(s16x8, bv);
      const float4* p2 = (const float4*)(W_hh + n * D_ + kt * 32 + lg * 8);
      float4 c0v = p2[0], c1v = p2[1];
      u32x4 cv;
      cv[0] = pk2(c0v.x * sc, c0v.y * sc); cv[1] = pk2(c0v.z * sc, c0v.w * sc);
      cv[2] = pk2(c1v.x * sc, c1v.y * sc); cv[3] = pk2(c1v.z * sc, c1v.w * sc);
      fhh[kt][g] = __builtin_bit_cast(s16x8, cv);
    }
  }
  // h LDS addresses (r7-proven swizzle)
  unsigned rd_[4];
  #pragma unroll
  for (int kt = 0; kt < 4; kt++)
    rd_[kt] = (unsigned)(hr * 256 + (((kt << 2) + lg) ^ ((hr & 1) << 2)) * 16);
  unsigned wr_ = (unsigned)(lg * 256 + ((d >> 3) ^ ((lg & 1) << 2)) * 16 + (d & 7) * 2);
  // G1 float4 idx: write m=lg*4+r ; read m=TS*4+lg (wave-local)
  int gw0 = lg * 512 + d;
  int gr0 = lg * 128 + d;
  // ring read addr (FIH A-frag): slot base added per group; same swizzle as h
  unsigned rrd[4];
  #pragma unroll
  for (int kt = 0; kt < 4; kt++)
    rrd[kt] = (unsigned)(ts * 1056 + br * 256 + (((kt << 2) + lg) ^ ((br & 1) << 2)) * 16);

  // prologue thread roles: (prow, pdq)
  int prow = tid >> 7, pdq = tid & 127;
  const float* xrow = x + ((size_t)(row0 + prow) * T_) * D_ + pdq;
  float* owp = out_w + ((size_t)(row0 + prow) * T_) * D_ + pdq;
  unsigned wxwr = (unsigned)(prow * 256 + (((pdq >> 3) ^ ((prow & 1) << 2)) << 4) + (pdq & 7) * 2);

  if (tid < T_) wxs[tid] = Wa[2 * D_ + tid];
  if (tid < 128) ((uint2*)hl)[tid] = make_uint2(0u, 0u);   // zero h buf0
  __syncthreads();

  // ---- x_part (coalesced single pass over x) + per-row softmax ----
  float xp = 0.f;
  #pragma unroll 5
  for (int t = 0; t < T_; t++) xp = fmaf(xrow[(size_t)t * D_], wxs[t], xp);
  rbuf[tid] = xp; __syncthreads();
  for (int s = 64; s >= 1; s >>= 1){
    if ((tid & 127) < s) rbuf[tid] = fmaxf(rbuf[tid], rbuf[tid + s]);
    __syncthreads();
  }
  float mx = rbuf[tid & 384];
  __syncthreads();
  float ev = __expf(xp - mx);
  rbuf[tid] = ev; __syncthreads();
  for (int s = 64; s >= 1; s >>= 1){
    if ((tid & 127) < s) rbuf[tid] += rbuf[tid + s];
    __syncthreads();
  }
  float attn_own = ev / rbuf[tid & 384];
  __syncthreads();

  // ---- prefill ring t=0..7 + out_w t=0..7 ----
  #pragma unroll
  for (int t = 0; t < 8; t++){
    float wv = attn_own * xrow[(size_t)t * D_];
    owp[(size_t)t * D_] = wv;
    *(unsigned short*)(ring + t * 1056 + wxwr) = bf1(wv);
  }
  float xv = xrow[(size_t)8 * D_];          // preload x[t=8]
  float* owp8 = owp + 8 * D_;               // out_w target t+8
  const float* xl9 = xrow + (size_t)9 * D_; // x load target t+9
  float* op = out_e + ((size_t)(row0 + lg) * T_) * D_ + d;
  float cst = 0.f;
  int tcur = 0, t12 = 0;
  __syncthreads();

#define BAR() do {                                                                  \
    asm volatile("s_waitcnt lgkmcnt(0)" ::: "memory");                              \
    __builtin_amdgcn_s_barrier();                                                   \
  } while (0)

  // ---- batch-fih: A from ring (slots gp3*4 + ts), 16 MFMA -> G1 (wave-local) ----
#define FIH(GP3) do {                                                               \
    s16x8 aaA[4];                                                                   \
    _Pragma("unroll")                                                               \
    for (int kt = 0; kt < 4; kt++)                                                  \
      aaA[kt] = *(const s16x8*)(ring + (GP3) * 4224 + rrd[kt]);                     \
    f32x4 p0 = {biasS[0], biasS[0], biasS[0], biasS[0]};                            \
    f32x4 p1 = {biasS[1], biasS[1], biasS[1], biasS[1]};                            \
    f32x4 p2 = {biasS[2], biasS[2], biasS[2], biasS[2]};                            \
    f32x4 p3 = {biasS[3], biasS[3], biasS[3], biasS[3]};                            \
    _Pragma("unroll")                                                               \
    for (int kt = 0; kt < 4; kt++){                                                 \
      p0 = __builtin_amdgcn_mfma_f32_16x16x32_bf16(aaA[kt], fih[kt][0], p0,0,0,0);  \
      p1 = __builtin_amdgcn_mfma_f32_16x16x32_bf16(aaA[kt], fih[kt][1], p1,0,0,0);  \
      p2 = __builtin_amdgcn_mfma_f32_16x16x32_bf16(aaA[kt], fih[kt][2], p2,0,0,0);  \
      p3 = __builtin_amdgcn_mfma_f32_16x16x32_bf16(aaA[kt], fih[kt][3], p3,0,0,0);  \
    }                                                                               \
    _Pragma("unroll")                                                               \
    for (int r = 0; r < 4; r++)                                                     \
      g1l[gw0 + r * 128] = make_float4(p0[r], p1[r], p2[r], p3[r]);                 \
  } while (0)

  // ---- one recurrence step; wx-pass for t+8 rides inside ----
#define STEP(TS) do {                                                               \
    s16x8 aa[4];                                                                    \
    _Pragma("unroll")                                                               \
    for (int kt = 0; kt < 4; kt++)                                                  \
      aa[kt] = *(const s16x8*)(hl + rd_[kt] + ((TS) & 1) * 1024);                   \
    float4 q = g1l[gr0 + (TS) * 512];                                               \
    f32x4 a0 = {q.x, q.x, q.x, q.x};                                                \
    f32x4 a1 = {q.y, q.y, q.y, q.y};                                                \
    f32x4 a2 = {q.z, q.z, q.z, q.z};                                                \
    f32x4 a3 = {q.w, q.w, q.w, q.w};                                                \
    _Pragma("unroll")                                                               \
    for (int kt = 0; kt < 4; kt++){                                                 \
      a0 = __builtin_amdgcn_mfma_f32_16x16x32_bf16(aa[kt], fhh[kt][0], a0,0,0,0);   \
      a1 = __builtin_amdgcn_mfma_f32_16x16x32_bf16(aa[kt], fhh[kt][1], a1,0,0,0);   \
      a2 = __builtin_amdgcn_mfma_f32_16x16x32_bf16(aa[kt], fhh[kt][2], a2,0,0,0);   \
      a3 = __builtin_amdgcn_mfma_f32_16x16x32_bf16(aa[kt], fhh[kt][3], a3,0,0,0);   \
    }                                                                               \
    if (tcur <= 246){                                                               \
      float wv = attn_own * xv;                                                     \
      *owp8 = wv; owp8 += D_;                                                       \
      int ws = (t12 >= 4) ? (t12 - 4) : (t12 + 8);                                  \
      *(unsigned short*)(ring + ws * 1056 + wxwr) = bf1(wv);                        \
      if (tcur <= 245){ xv = *xl9; xl9 += D_; }                                     \
    }                                                                               \
    tcur++; t12 = (t12 == 11) ? 0 : t12 + 1;                                        \
    float gi = a0[0], gf = a1[0], gg = a2[0], go = a3[0];                           \
    float cn = fmaf(sg(gf), cst, sg(gi) * tg(gg));                                  \
    float hn = sg(go) * tc_(cn); cst = cn;                                          \
    *op = hn; op += D_;                                                             \
    *(unsigned short*)(hl + wr_ + (1 - ((TS) & 1)) * 1024) = bf1(hn);               \
    BAR();                                                                          \
  } while (0)

  int gp3 = 0;
  for (int g = 0; g < 63; g++){
    FIH(gp3);
    STEP(0); STEP(1); STEP(2); STEP(3);
    gp3 = (gp3 == 2) ? 0 : gp3 + 1;
  }
  FIH(gp3);                       // g=63 (63%3==0): t=252..255; ts=3 garbage unused
  STEP(0); STEP(1); STEP(2);      // t = 252, 253, 254
#undef FIH
#undef STEP
#undef BAR
}

extern "C" void kernel_launch(void* const* d_in, const int* in_sizes, int n_in,
                              void* d_out, int out_size, void* d_ws, size_t ws_size,
                              hipStream_t stream) {
  (void)in_sizes; (void)n_in; (void)out_size; (void)d_ws; (void)ws_size;
  const float* x    = (const float*)d_in[0];
  const float* Wa   = (const float*)d_in[1];
  // d_in[2] = ba : dead (softmax shift invariance); Wh/Wc parts of Wa also dead
  const float* W_ih = (const float*)d_in[3];
  const float* W_hh = (const float*)d_in[4];
  const float* b_ih = (const float*)d_in[5];
  const float* b_hh = (const float*)d_in[6];
  float* out_w = (float*)d_out;
  float* out_e = out_w + (size_t)B_ * T_ * D_;

  k_fused<<<256, 512, 0, stream>>>(x, Wa, W_ih, W_hh, b_ih, b_hh, out_w, out_e);
}

// Round 12
// 285.307 us; speedup vs baseline: 1.0874x; 1.0727x over previous
//
#include <hip/hip_runtime.h>
#include <hip/hip_bf16.h>
#include <stdint.h>

#define B_ 1024
#define T_ 255
#define D_ 128

typedef float f32x4 __attribute__((ext_vector_type(4)));
typedef short s16x8 __attribute__((ext_vector_type(8)));
typedef unsigned u32x4 __attribute__((ext_vector_type(4)));

__device__ __forceinline__ unsigned pk2(float a, float b){
  __hip_bfloat162 h2 = __float22bfloat162_rn(make_float2(a, b));  // v_cvt_pk_bf16_f32
  union { __hip_bfloat162 h; unsigned u; } c; c.h = h2; return c.u;
}
__device__ __forceinline__ unsigned short bf1(float a){
  __hip_bfloat16 h = __float2bfloat16(a);
  union { __hip_bfloat16 h; unsigned short u; } c; c.h = h; return c.u;
}
// gates arrive pre-scaled by log2e (2*log2e for the g gate): raw v_exp (= 2^x)
__device__ __forceinline__ float sg(float x){       // sigmoid(orig), x = log2e*orig
  return __builtin_amdgcn_rcpf(1.f + __builtin_amdgcn_exp2f(-x));
}
__device__ __forceinline__ float tg(float x){       // tanh(orig), x = 2*log2e*orig
  return fmaf(-2.f, __builtin_amdgcn_rcpf(1.f + __builtin_amdgcn_exp2f(x)), 1.f);
}
__device__ __forceinline__ float tc_(float c){      // tanh(c), c unscaled
  return fmaf(-2.f, __builtin_amdgcn_rcpf(1.f + __builtin_amdgcn_exp2f(c * 2.88539008f)), 1.f);
}

// ---------------- Kernel 1: softmax(x_part) ; out_w = attn*x (f32 only) ---------
__global__ __launch_bounds__(512) void k_attn(const float* __restrict__ x,
    const float* __restrict__ Wa, float* __restrict__ out_w){
  extern __shared__ float4 xs4[];          // 8160 float4 = 130560 B
  __shared__ float wxs[256];
  __shared__ float part_s[16][128];
  __shared__ float red[128];
  __shared__ float attn_s[128];
  int tid = threadIdx.x, b = blockIdx.x;
  if (tid < T_) wxs[tid] = Wa[2 * D_ + tid];
  __syncthreads();
  const float4* xg = (const float4*)(x + (size_t)b * T_ * D_);
  float4 acc = {0.f, 0.f, 0.f, 0.f};
  for (int i = tid; i < 8160; i += 512){
    float4 v = xg[i];
    xs4[i] = v;
    float wt = wxs[i >> 5];
    acc.x += v.x * wt; acc.y += v.y * wt; acc.z += v.z * wt; acc.w += v.w * wt;
  }
  int d0 = (tid & 31) * 4, s = tid >> 5;
  *(float4*)&part_s[s][d0] = acc;
  __syncthreads();
  if (tid < 128){
    float v = 0.f;
    #pragma unroll
    for (int k = 0; k < 16; k++) v += part_s[k][tid];
    red[tid] = v; attn_s[tid] = v;
  }
  __syncthreads();
  for (int st = 64; st >= 1; st >>= 1){
    if (tid < st) red[tid] = fmaxf(red[tid], red[tid + st]);
    __syncthreads();
  }
  float mx = red[0];
  __syncthreads();
  float ev = 0.f;
  if (tid < 128){ ev = __expf(attn_s[tid] - mx); red[tid] = ev; }
  __syncthreads();
  for (int st = 64; st >= 1; st >>= 1){
    if (tid < st) red[tid] += red[tid + st];
    __syncthreads();
  }
  float sm = red[0];
  if (tid < 128) attn_s[tid] = ev / sm;
  __syncthreads();
  float4 at = *(const float4*)&attn_s[d0];
  float4* owg = (float4*)(out_w + (size_t)b * T_ * D_);
  for (int i = tid; i < 8160; i += 512){
    float4 v = xs4[i];
    float4 wv; wv.x = v.x*at.x; wv.y = v.y*at.y; wv.z = v.z*at.z; wv.w = v.w*at.w;
    owg[i] = wv;
  }
}

// ---------------- Kernel 2: fused recurrence (r7 core). 256 blk x 4 rows x 8 waves
// FIH A-source = out_w f32 (no wxb workspace): per group load 8 float4, v_cvt_pk
// to bf16 frags (off critical path). Gates pre-scaled by log2e (exp2 trans, r11-
// verified); G1 enters fhh MFMAs as C-init (r11-verified).
__global__ __launch_bounds__(512, 2) void k_rnn(const float* __restrict__ W_ih,
    const float* __restrict__ W_hh, const float* __restrict__ b_ih,
    const float* __restrict__ b_hh, const float* __restrict__ wxf,
    float* __restrict__ out_e){
  __shared__ char hl[2048];      // h bf16 [buf][row 256B][slot 16B], slot^=(row&1)<<2
  __shared__ float4 g1l[2048];   // 32 KB f32 G1: [m=ts*4+br][d] {i,f,g,o} (scaled)
  int tid = threadIdx.x;
  int lane = tid & 63, w = tid >> 6;
  int l15 = lane & 15, lg = lane >> 4;
  int row0 = blockIdx.x << 2;
  int d = w * 16 + l15;
  int hr = l15 >> 2;             // h row this lane reads (x4 replication)
  int ts = l15 >> 2, br = l15 & 3;   // FIH A row decode (timestep-slot, batch-row)

  // weight B-fragments [kt][gate], k = kt*32 + lg*8 + j ; scaled by log2e per gate
  const float SC0 = 1.44269504f, SC2 = 2.88539008f;
  s16x8 fih[4][4], fhh[4][4];
  float biasS[4];
  #pragma unroll
  for (int g = 0; g < 4; g++){
    float sc = (g == 2) ? SC2 : SC0;
    int n = g * 128 + d;
    biasS[g] = (b_ih[n] + b_hh[n]) * sc;
    #pragma unroll
    for (int kt = 0; kt < 4; kt++){
      const float4* p1 = (const float4*)(W_ih + n * D_ + kt * 32 + lg * 8);
      float4 a0 = p1[0], a1 = p1[1];
      u32x4 bv;
      bv[0] = pk2(a0.x * sc, a0.y * sc); bv[1] = pk2(a0.z * sc, a0.w * sc);
      bv[2] = pk2(a1.x * sc, a1.y * sc); bv[3] = pk2(a1.z * sc, a1.w * sc);
      fih[kt][g] = __builtin_bit_cast(s16x8, bv);
      const float4* p2 = (const float4*)(W_hh + n * D_ + kt * 32 + lg * 8);
      float4 c0v = p2[0], c1v = p2[1];
      u32x4 cv;
      cv[0] = pk2(c0v.x * sc, c0v.y * sc); cv[1] = pk2(c0v.z * sc, c0v.w * sc);
      cv[2] = pk2(c1v.x * sc, c1v.y * sc); cv[3] = pk2(c1v.z * sc, c1v.w * sc);
      fhh[kt][g] = __builtin_bit_cast(s16x8, cv);
    }
  }
  // h LDS addresses (r7-proven swizzle)
  unsigned rd_[4];
  #pragma unroll
  for (int kt = 0; kt < 4; kt++)
    rd_[kt] = (unsigned)(hr * 256 + (((kt << 2) + lg) ^ ((hr & 1) << 2)) * 16);
  unsigned wr_ = (unsigned)(lg * 256 + ((d >> 3) ^ ((lg & 1) << 2)) * 16 + (d & 7) * 2);
  // G1 float4 idx: write m=lg*4+r ; read m=TS*4+lg (wave-local)
  int gw0 = lg * 512 + d;
  int gr0 = lg * 128 + d;

  float* op = out_e + (size_t)(row0 + lg) * T_ * D_ + d;
  float cst = 0.f;
  if (tid < 128) ((uint2*)hl)[tid] = make_uint2(0u, 0u);   // zero h buf0 (1 KB)

  // FIH A stream from out_w f32: lane reads row (row0+br), t = 4g+ts, cols lg*8
  const float* wp = wxf + ((size_t)(row0 + br) * T_ + ts) * D_ + lg * 8;
  float4 PA[8];                              // group buffer: 8 float4 (32 f32)
  #pragma unroll
  for (int kt = 0; kt < 4; kt++){
    PA[2*kt]   = *(const float4*)(wp + kt * 32);
    PA[2*kt+1] = *(const float4*)(wp + kt * 32 + 4);
  }
  __syncthreads();

#define BAR() do {                                                                  \
    asm volatile("s_waitcnt lgkmcnt(0)" ::: "memory");                              \
    __builtin_amdgcn_s_barrier();                                                   \
  } while (0)

  // ---- batch-fih: convert PA -> bf16 frags, prefetch next group, 16 MFMA -> G1 --
#define FIH(GNEXT, LAST) do {                                                       \
    s16x8 aaA[4];                                                                   \
    _Pragma("unroll")                                                               \
    for (int kt = 0; kt < 4; kt++){                                                 \
      u32x4 av;                                                                     \
      av[0] = pk2(PA[2*kt].x,   PA[2*kt].y);                                        \
      av[1] = pk2(PA[2*kt].z,   PA[2*kt].w);                                        \
      av[2] = pk2(PA[2*kt+1].x, PA[2*kt+1].y);                                      \
      av[3] = pk2(PA[2*kt+1].z, PA[2*kt+1].w);                                      \
      aaA[kt] = __builtin_bit_cast(s16x8, av);                                      \
    }                                                                               \
    if (!(LAST)){                                                                   \
      const float* np = wp + (size_t)(GNEXT) * (4 * D_);                            \
      _Pragma("unroll")                                                             \
      for (int kt = 0; kt < 4; kt++){                                               \
        PA[2*kt]   = *(const float4*)(np + kt * 32);                                \
        PA[2*kt+1] = *(const float4*)(np + kt * 32 + 4);                            \
      }                                                                             \
    }                                                                               \
    f32x4 p0 = {biasS[0], biasS[0], biasS[0], biasS[0]};                            \
    f32x4 p1 = {biasS[1], biasS[1], biasS[1], biasS[1]};                            \
    f32x4 p2 = {biasS[2], biasS[2], biasS[2], biasS[2]};                            \
    f32x4 p3 = {biasS[3], biasS[3], biasS[3], biasS[3]};                            \
    _Pragma("unroll")                                                               \
    for (int kt = 0; kt < 4; kt++){                                                 \
      p0 = __builtin_amdgcn_mfma_f32_16x16x32_bf16(aaA[kt], fih[kt][0], p0,0,0,0);  \
      p1 = __builtin_amdgcn_mfma_f32_16x16x32_bf16(aaA[kt], fih[kt][1], p1,0,0,0);  \
      p2 = __builtin_amdgcn_mfma_f32_16x16x32_bf16(aaA[kt], fih[kt][2], p2,0,0,0);  \
      p3 = __builtin_amdgcn_mfma_f32_16x16x32_bf16(aaA[kt], fih[kt][3], p3,0,0,0);  \
    }                                                                               \
    _Pragma("unroll")                                                               \
    for (int r = 0; r < 4; r++)                                                     \
      g1l[gw0 + r * 128] = make_float4(p0[r], p1[r], p2[r], p3[r]);                 \
  } while (0)

  // ---- one recurrence step (TS compile-time 0..3; h buf parity = TS&1) ----
#define STEP(TS) do {                                                               \
    s16x8 aa[4];                                                                    \
    _Pragma("unroll")                                                               \
    for (int kt = 0; kt < 4; kt++)                                                  \
      aa[kt] = *(const s16x8*)(hl + rd_[kt] + ((TS) & 1) * 1024);                   \
    float4 q = g1l[gr0 + (TS) * 512];                                               \
    f32x4 a0 = {q.x, q.x, q.x, q.x};                                                \
    f32x4 a1 = {q.y, q.y, q.y, q.y};                                                \
    f32x4 a2 = {q.z, q.z, q.z, q.z};                                                \
    f32x4 a3 = {q.w, q.w, q.w, q.w};                                                \
    _Pragma("unroll")                                                               \
    for (int kt = 0; kt < 4; kt++){                                                 \
      a0 = __builtin_amdgcn_mfma_f32_16x16x32_bf16(aa[kt], fhh[kt][0], a0,0,0,0);   \
      a1 = __builtin_amdgcn_mfma_f32_16x16x32_bf16(aa[kt], fhh[kt][1], a1,0,0,0);   \
      a2 = __builtin_amdgcn_mfma_f32_16x16x32_bf16(aa[kt], fhh[kt][2], a2,0,0,0);   \
      a3 = __builtin_amdgcn_mfma_f32_16x16x32_bf16(aa[kt], fhh[kt][3], a3,0,0,0);   \
    }                                                                               \
    float cn = fmaf(sg(a1[0]), cst, sg(a0[0]) * tg(a2[0]));                         \
    float hn = sg(a3[0]) * tc_(cn); cst = cn;                                       \
    *op = hn; op += D_;                                                             \
    *(unsigned short*)(hl + wr_ + (1 - ((TS) & 1)) * 1024) = bf1(hn);               \
    BAR();                                                                          \
  } while (0)

  for (int g = 0; g < 63; g++){
    FIH(g + 1, false);
    STEP(0); STEP(1); STEP(2); STEP(3);
  }
  FIH(64, true);                  // group 63: t = 252..254 (+1 garbage slot unused)
  STEP(0); STEP(1); STEP(2);
#undef FIH
#undef STEP
#undef BAR
}

extern "C" void kernel_launch(void* const* d_in, const int* in_sizes, int n_in,
                              void* d_out, int out_size, void* d_ws, size_t ws_size,
                              hipStream_t stream) {
  (void)in_sizes; (void)n_in; (void)out_size; (void)d_ws; (void)ws_size;
  const float* x    = (const float*)d_in[0];
  const float* Wa   = (const float*)d_in[1];
  // d_in[2] = ba : dead (softmax shift invariance); Wh/Wc parts of Wa also dead
  const float* W_ih = (const float*)d_in[3];
  const float* W_hh = (const float*)d_in[4];
  const float* b_ih = (const float*)d_in[5];
  const float* b_hh = (const float*)d_in[6];
  float* out_w = (float*)d_out;
  float* out_e = out_w + (size_t)B_ * T_ * D_;

  k_attn<<<B_, 512, 130560, stream>>>(x, Wa, out_w);
  k_rnn <<<256, 512, 0, stream>>>(W_ih, W_hh, b_ih, b_hh, out_w, out_e);
}

// Round 13
// 245.564 us; speedup vs baseline: 1.2633x; 1.1618x over previous
//
#include <hip/hip_runtime.h>
#include <hip/hip_bf16.h>
#include <stdint.h>

#define B_ 1024
#define T_ 255
#define D_ 128

typedef float f32x4 __attribute__((ext_vector_type(4)));
typedef short s16x8 __attribute__((ext_vector_type(8)));
typedef unsigned u32x4 __attribute__((ext_vector_type(4)));

__device__ __forceinline__ unsigned pk2(float a, float b){
  __hip_bfloat162 h2 = __float22bfloat162_rn(make_float2(a, b));  // v_cvt_pk_bf16_f32
  union { __hip_bfloat162 h; unsigned u; } c; c.h = h2; return c.u;
}
__device__ __forceinline__ unsigned short bf1(float a){
  __hip_bfloat16 h = __float2bfloat16(a);
  union { __hip_bfloat16 h; unsigned short u; } c; c.h = h; return c.u;
}
// gates arrive pre-scaled by log2e (2*log2e for the g gate): raw v_exp (= 2^x)
__device__ __forceinline__ float sg(float x){       // sigmoid(orig), x = log2e*orig
  return __builtin_amdgcn_rcpf(1.f + __builtin_amdgcn_exp2f(-x));
}
__device__ __forceinline__ float tg(float x){       // tanh(orig), x = 2*log2e*orig
  return fmaf(-2.f, __builtin_amdgcn_rcpf(1.f + __builtin_amdgcn_exp2f(x)), 1.f);
}
__device__ __forceinline__ float tc_(float c){      // tanh(c), c unscaled
  return fmaf(-2.f, __builtin_amdgcn_rcpf(1.f + __builtin_amdgcn_exp2f(c * 2.88539008f)), 1.f);
}

// ---------------- Kernel 1: softmax(x_part) ; out_w = attn*x ; wx bf16 ----------
// Also zeroes this block's slice of the t=255 pad slot (replaces the memset dispatch).
__global__ __launch_bounds__(512) void k_attn(const float* __restrict__ x,
    const float* __restrict__ Wa, float* __restrict__ out_w,
    uint2* __restrict__ wxq){
  extern __shared__ float4 xs4[];          // 8160 float4 = 130560 B
  __shared__ float wxs[256];
  __shared__ float part_s[16][128];
  __shared__ float red[128];
  __shared__ float attn_s[128];
  int tid = threadIdx.x, b = blockIdx.x;
  if (tid < T_) wxs[tid] = Wa[2 * D_ + tid];
  if (tid >= 480) wxq[((size_t)T_ * B_ + b) * 32 + (tid - 480)] = make_uint2(0u, 0u);
  __syncthreads();
  const float4* xg = (const float4*)(x + (size_t)b * T_ * D_);
  float4 acc = {0.f, 0.f, 0.f, 0.f};
  for (int i = tid; i < 8160; i += 512){
    float4 v = xg[i];
    xs4[i] = v;
    float wt = wxs[i >> 5];
    acc.x += v.x * wt; acc.y += v.y * wt; acc.z += v.z * wt; acc.w += v.w * wt;
  }
  int d0 = (tid & 31) * 4, s = tid >> 5;
  *(float4*)&part_s[s][d0] = acc;
  __syncthreads();
  if (tid < 128){
    float v = 0.f;
    #pragma unroll
    for (int k = 0; k < 16; k++) v += part_s[k][tid];
    red[tid] = v; attn_s[tid] = v;
  }
  __syncthreads();
  for (int st = 64; st >= 1; st >>= 1){
    if (tid < st) red[tid] = fmaxf(red[tid], red[tid + st]);
    __syncthreads();
  }
  float mx = red[0];
  __syncthreads();
  float ev = 0.f;
  if (tid < 128){ ev = __expf(attn_s[tid] - mx); red[tid] = ev; }
  __syncthreads();
  for (int st = 64; st >= 1; st >>= 1){
    if (tid < st) red[tid] += red[tid + st];
    __syncthreads();
  }
  float sm = red[0];
  if (tid < 128) attn_s[tid] = ev / sm;
  __syncthreads();
  float4 at = *(const float4*)&attn_s[d0];
  float4* owg = (float4*)(out_w + (size_t)b * T_ * D_);
  for (int i = tid; i < 8160; i += 512){
    float4 v = xs4[i];
    float4 wv; wv.x = v.x*at.x; wv.y = v.y*at.y; wv.z = v.z*at.z; wv.w = v.w*at.w;
    owg[i] = wv;
    int t = i >> 5;
    uint2 q;
    q.x = pk2(wv.x, wv.y);
    q.y = pk2(wv.z, wv.w);
    wxq[((size_t)t * B_ + b) * 32 + (i & 31)] = q;   // [t][b][d] bf16 row-major
  }
}

// ---------------- Kernel 2: fused recurrence (r7 core). 256 blk x 4 rows x 8 waves
// r7-identical load paths (bf16 wxb A-stream, 2-group AF prefetch, h/G1 swizzles).
// STEP micro-opts (r11/r12-verified): exp2 pre-scaled gates; G1 as MFMA C-init.
__global__ __launch_bounds__(512, 2) void k_rnn(const float* __restrict__ W_ih,
    const float* __restrict__ W_hh, const float* __restrict__ b_ih,
    const float* __restrict__ b_hh, const unsigned short* __restrict__ wxb,
    float* __restrict__ out_e){
  __shared__ char hl[2048];      // h bf16 [buf][row 256B][slot 16B], slot^=(row&1)<<2
  __shared__ float4 g1l[2048];   // 32 KB f32 G1: [m=ts*4+br][d] {i,f,g,o} (scaled)
  int tid = threadIdx.x;
  int lane = tid & 63, w = tid >> 6;
  int l15 = lane & 15, lg = lane >> 4;
  int row0 = blockIdx.x << 2;
  int d = w * 16 + l15;
  int hr = l15 >> 2;             // h row this lane reads (x4 replication)

  // weight B-fragments [kt][gate], k = kt*32 + lg*8 + j ; scaled by log2e per gate
  const float SC0 = 1.44269504f, SC2 = 2.88539008f;
  s16x8 fih[4][4], fhh[4][4];
  float biasS[4];
  #pragma unroll
  for (int g = 0; g < 4; g++){
    float sc = (g == 2) ? SC2 : SC0;
    int n = g * 128 + d;
    biasS[g] = (b_ih[n] + b_hh[n]) * sc;
    #pragma unroll
    for (int kt = 0; kt < 4; kt++){
      const float4* p1 = (const float4*)(W_ih + n * D_ + kt * 32 + lg * 8);
      float4 a0 = p1[0], a1 = p1[1];
      u32x4 bv;
      bv[0] = pk2(a0.x * sc, a0.y * sc); bv[1] = pk2(a0.z * sc, a0.w * sc);
      bv[2] = pk2(a1.x * sc, a1.y * sc); bv[3] = pk2(a1.z * sc, a1.w * sc);
      fih[kt][g] = __builtin_bit_cast(s16x8, bv);
      const float4* p2 = (const float4*)(W_hh + n * D_ + kt * 32 + lg * 8);
      float4 c0v = p2[0], c1v = p2[1];
      u32x4 cv;
      cv[0] = pk2(c0v.x * sc, c0v.y * sc); cv[1] = pk2(c0v.z * sc, c0v.w * sc);
      cv[2] = pk2(c1v.x * sc, c1v.y * sc); cv[3] = pk2(c1v.z * sc, c1v.w * sc);
      fhh[kt][g] = __builtin_bit_cast(s16x8, cv);
    }
  }
  // h LDS addresses (r7-proven swizzle)
  unsigned rd_[4];
  #pragma unroll
  for (int kt = 0; kt < 4; kt++)
    rd_[kt] = (unsigned)(hr * 256 + (((kt << 2) + lg) ^ ((hr & 1) << 2)) * 16);
  unsigned wr_ = (unsigned)(lg * 256 + ((d >> 3) ^ ((lg & 1) << 2)) * 16 + (d & 7) * 2);
  // G1 float4 idx: write m=lg*4+r ; read m=TS*4+lg (wave-local)
  int gw0 = lg * 512 + d;
  int gr0 = lg * 128 + d;

  float* op = out_e + (size_t)(row0 + lg) * T_ * D_ + d;
  float cst = 0.f;
  if (tid < 128) ((uint2*)hl)[tid] = make_uint2(0u, 0u);   // zero h buf0 (1 KB)

  // fih A stream (r7-identical): wx[4g + (l15>>2)][row0 + (l15&3)][k-slice lg*8]
  const unsigned short* wpb = wxb + ((size_t)(l15 >> 2) * B_ + row0 + (l15 & 3)) * D_ + lg * 8;
  const size_t GSTRIDE = (size_t)4 * B_ * D_;               // 4 timesteps
  s16x8 AF0[4], AF1[4];
  #pragma unroll
  for (int kt = 0; kt < 4; kt++) AF0[kt] = *(const s16x8*)(wpb + kt * 32);
  #pragma unroll
  for (int kt = 0; kt < 4; kt++) AF1[kt] = *(const s16x8*)(wpb + GSTRIDE + kt * 32);
  __syncthreads();

#define BAR() do {                                                                  \
    asm volatile("s_waitcnt lgkmcnt(0)" ::: "memory");                              \
    __builtin_amdgcn_s_barrier();                                                   \
  } while (0)

  // ---- batch-fih: 16 MFMA -> f32 G1 (scaled) for 4 steps -> LDS (wave-local) ----
#define FIH_BATCH(AF) do {                                                          \
    f32x4 p0 = {biasS[0], biasS[0], biasS[0], biasS[0]};                            \
    f32x4 p1 = {biasS[1], biasS[1], biasS[1], biasS[1]};                            \
    f32x4 p2 = {biasS[2], biasS[2], biasS[2], biasS[2]};                            \
    f32x4 p3 = {biasS[3], biasS[3], biasS[3], biasS[3]};                            \
    _Pragma("unroll")                                                               \
    for (int kt = 0; kt < 4; kt++){                                                 \
      p0 = __builtin_amdgcn_mfma_f32_16x16x32_bf16(AF[kt], fih[kt][0], p0,0,0,0);   \
      p1 = __builtin_amdgcn_mfma_f32_16x16x32_bf16(AF[kt], fih[kt][1], p1,0,0,0);   \
      p2 = __builtin_amdgcn_mfma_f32_16x16x32_bf16(AF[kt], fih[kt][2], p2,0,0,0);   \
      p3 = __builtin_amdgcn_mfma_f32_16x16x32_bf16(AF[kt], fih[kt][3], p3,0,0,0);   \
    }                                                                               \
    _Pragma("unroll")                                                               \
    for (int r = 0; r < 4; r++)                                                     \
      g1l[gw0 + r * 128] = make_float4(p0[r], p1[r], p2[r], p3[r]);                 \
  } while (0)

  // ---- one recurrence step (TS compile-time 0..3; h buf parity = TS&1) ----
#define STEP(TS) do {                                                               \
    s16x8 aa[4];                                                                    \
    _Pragma("unroll")                                                               \
    for (int kt = 0; kt < 4; kt++)                                                  \
      aa[kt] = *(const s16x8*)(hl + rd_[kt] + ((TS) & 1) * 1024);                   \
    float4 q = g1l[gr0 + (TS) * 512];                                               \
    f32x4 a0 = {q.x, q.x, q.x, q.x};                                                \
    f32x4 a1 = {q.y, q.y, q.y, q.y};                                                \
    f32x4 a2 = {q.z, q.z, q.z, q.z};                                                \
    f32x4 a3 = {q.w, q.w, q.w, q.w};                                                \
    _Pragma("unroll")                                                               \
    for (int kt = 0; kt < 4; kt++){                                                 \
      a0 = __builtin_amdgcn_mfma_f32_16x16x32_bf16(aa[kt], fhh[kt][0], a0,0,0,0);   \
      a1 = __builtin_amdgcn_mfma_f32_16x16x32_bf16(aa[kt], fhh[kt][1], a1,0,0,0);   \
      a2 = __builtin_amdgcn_mfma_f32_16x16x32_bf16(aa[kt], fhh[kt][2], a2,0,0,0);   \
      a3 = __builtin_amdgcn_mfma_f32_16x16x32_bf16(aa[kt], fhh[kt][3], a3,0,0,0);   \
    }                                                                               \
    float cn = fmaf(sg(a1[0]), cst, sg(a0[0]) * tg(a2[0]));                         \
    float hn = sg(a3[0]) * tc_(cn); cst = cn;                                       \
    *op = hn; op += D_;                                                             \
    *(unsigned short*)(hl + wr_ + (1 - ((TS) & 1)) * 1024) = bf1(hn);               \
    BAR();                                                                          \
  } while (0)

  for (int g = 0; g < 62; g += 2){
    FIH_BATCH(AF0);
    #pragma unroll
    for (int kt = 0; kt < 4; kt++)
      AF0[kt] = *(const s16x8*)(wpb + (size_t)(g + 2) * GSTRIDE + kt * 32);
    STEP(0); STEP(1); STEP(2); STEP(3);
    FIH_BATCH(AF1);
    #pragma unroll
    for (int kt = 0; kt < 4; kt++)
      AF1[kt] = *(const s16x8*)(wpb + (size_t)(g + 3) * GSTRIDE + kt * 32);
    STEP(0); STEP(1); STEP(2); STEP(3);
  }
  FIH_BATCH(AF0);                         // group 62: t = 248..251
  STEP(0); STEP(1); STEP(2); STEP(3);
  FIH_BATCH(AF1);                         // group 63: t = 252..254 (+zero pad)
  STEP(0); STEP(1); STEP(2);
#undef FIH_BATCH
#undef STEP
#undef BAR
}

extern "C" void kernel_launch(void* const* d_in, const int* in_sizes, int n_in,
                              void* d_out, int out_size, void* d_ws, size_t ws_size,
                              hipStream_t stream) {
  (void)in_sizes; (void)n_in; (void)out_size;
  const float* x    = (const float*)d_in[0];
  const float* Wa   = (const float*)d_in[1];
  // d_in[2] = ba : dead (softmax shift invariance); Wh/Wc parts of Wa also dead
  const float* W_ih = (const float*)d_in[3];
  const float* W_hh = (const float*)d_in[4];
  const float* b_ih = (const float*)d_in[5];
  const float* b_hh = (const float*)d_in[6];
  float* out_w = (float*)d_out;
  float* out_e = out_w + (size_t)B_ * T_ * D_;
  unsigned short* wxb = (unsigned short*)d_ws;   // [t][b][d] bf16; T+1 slots
  size_t need = (size_t)(T_ + 1) * B_ * D_ * 2;  // 67.1 MB (t=255 pad, zeroed by k_attn)
  if (ws_size < need) return;

  k_attn<<<B_, 512, 130560, stream>>>(x, Wa, out_w, (uint2*)wxb);
  k_rnn <<<256, 512, 0, stream>>>(W_ih, W_hh, b_ih, b_hh, wxb, out_e);
}

// Round 14
// 230.381 us; speedup vs baseline: 1.3466x; 1.0659x over previous
//
#include <hip/hip_runtime.h>
#include <hip/hip_bf16.h>
#include <stdint.h>

#define B_ 1024
#define T_ 255
#define D_ 128

typedef float f32x4 __attribute__((ext_vector_type(4)));
typedef short s16x8 __attribute__((ext_vector_type(8)));
typedef unsigned u32x4 __attribute__((ext_vector_type(4)));

__device__ __forceinline__ unsigned pk2(float a, float b){
  __hip_bfloat162 h2 = __float22bfloat162_rn(make_float2(a, b));  // v_cvt_pk_bf16_f32
  union { __hip_bfloat162 h; unsigned u; } c; c.h = h2; return c.u;
}
__device__ __forceinline__ unsigned short bf1(float a){
  __hip_bfloat16 h = __float2bfloat16(a);
  union { __hip_bfloat16 h; unsigned short u; } c; c.h = h; return c.u;
}
// gates arrive pre-scaled by log2e (2*log2e for the g gate): raw v_exp (= 2^x)
__device__ __forceinline__ float sg(float x){       // sigmoid(orig), x = log2e*orig
  return __builtin_amdgcn_rcpf(1.f + __builtin_amdgcn_exp2f(-x));
}
__device__ __forceinline__ float tg(float x){       // tanh(orig), x = 2*log2e*orig
  return fmaf(-2.f, __builtin_amdgcn_rcpf(1.f + __builtin_amdgcn_exp2f(x)), 1.f);
}
__device__ __forceinline__ float tc_(float c){      // tanh(c), c unscaled
  return fmaf(-2.f, __builtin_amdgcn_rcpf(1.f + __builtin_amdgcn_exp2f(c * 2.88539008f)), 1.f);
}

// ---------------- Kernel 1: softmax(x_part) ; out_w = attn*x ; wx bf16 ----------
// Also zeroes this block's slice of the t=255 pad slot (replaces memset dispatch).
__global__ __launch_bounds__(512) void k_attn(const float* __restrict__ x,
    const float* __restrict__ Wa, float* __restrict__ out_w,
    uint2* __restrict__ wxq){
  extern __shared__ float4 xs4[];          // 8160 float4 = 130560 B
  __shared__ float wxs[256];
  __shared__ float part_s[16][128];
  __shared__ float red[128];
  __shared__ float attn_s[128];
  int tid = threadIdx.x, b = blockIdx.x;
  if (tid < T_) wxs[tid] = Wa[2 * D_ + tid];
  if (tid >= 480) wxq[((size_t)T_ * B_ + b) * 32 + (tid - 480)] = make_uint2(0u, 0u);
  __syncthreads();
  const float4* xg = (const float4*)(x + (size_t)b * T_ * D_);
  float4 acc = {0.f, 0.f, 0.f, 0.f};
  for (int i = tid; i < 8160; i += 512){
    float4 v = xg[i];
    xs4[i] = v;
    float wt = wxs[i >> 5];
    acc.x += v.x * wt; acc.y += v.y * wt; acc.z += v.z * wt; acc.w += v.w * wt;
  }
  int d0 = (tid & 31) * 4, s = tid >> 5;
  *(float4*)&part_s[s][d0] = acc;
  __syncthreads();
  if (tid < 128){
    float v = 0.f;
    #pragma unroll
    for (int k = 0; k < 16; k++) v += part_s[k][tid];
    red[tid] = v; attn_s[tid] = v;
  }
  __syncthreads();
  for (int st = 64; st >= 1; st >>= 1){
    if (tid < st) red[tid] = fmaxf(red[tid], red[tid + st]);
    __syncthreads();
  }
  float mx = red[0];
  __syncthreads();
  float ev = 0.f;
  if (tid < 128){ ev = __expf(attn_s[tid] - mx); red[tid] = ev; }
  __syncthreads();
  for (int st = 64; st >= 1; st >>= 1){
    if (tid < st) red[tid] += red[tid + st];
    __syncthreads();
  }
  float sm = red[0];
  if (tid < 128) attn_s[tid] = ev / sm;
  __syncthreads();
  float4 at = *(const float4*)&attn_s[d0];
  float4* owg = (float4*)(out_w + (size_t)b * T_ * D_);
  for (int i = tid; i < 8160; i += 512){
    float4 v = xs4[i];
    float4 wv; wv.x = v.x*at.x; wv.y = v.y*at.y; wv.z = v.z*at.z; wv.w = v.w*at.w;
    owg[i] = wv;
    int t = i >> 5;
    uint2 q;
    q.x = pk2(wv.x, wv.y);
    q.y = pk2(wv.z, wv.w);
    wxq[((size_t)t * B_ + b) * 32 + (i & 31)] = q;   // [t][b][d] bf16 row-major
  }
}

// ---------------- Kernel 2: fused recurrence (r7-exact skeleton) ----------------
// 256 blocks x 4 rows x 512 thr. STEP: zero-init accs, G1 adds AFTER the MFMA
// chain (r7-proven overlap); exp2 pre-scaled gates (r11/r13-verified numerics).
__global__ __launch_bounds__(512, 2) void k_rnn(const float* __restrict__ W_ih,
    const float* __restrict__ W_hh, const float* __restrict__ b_ih,
    const float* __restrict__ b_hh, const unsigned short* __restrict__ wxb,
    float* __restrict__ out_e){
  __shared__ char hl[2048];      // h bf16 [buf][row 256B][slot 16B], slot^=(row&1)<<2
  __shared__ float4 g1l[2048];   // 32 KB f32 G1: [m=ts*4+br][d] {i,f,g,o} (scaled)
  int tid = threadIdx.x;
  int lane = tid & 63, w = tid >> 6;
  int l15 = lane & 15, lg = lane >> 4;
  int row0 = blockIdx.x << 2;
  int d = w * 16 + l15;
  int hr = l15 >> 2;             // h row this lane reads (x4 replication)

  // weight B-fragments [kt][gate], k = kt*32 + lg*8 + j ; scaled by log2e per gate
  const float SC0 = 1.44269504f, SC2 = 2.88539008f;
  s16x8 fih[4][4], fhh[4][4];
  float biasS[4];
  #pragma unroll
  for (int g = 0; g < 4; g++){
    float sc = (g == 2) ? SC2 : SC0;
    int n = g * 128 + d;
    biasS[g] = (b_ih[n] + b_hh[n]) * sc;
    #pragma unroll
    for (int kt = 0; kt < 4; kt++){
      const float4* p1 = (const float4*)(W_ih + n * D_ + kt * 32 + lg * 8);
      float4 a0 = p1[0], a1 = p1[1];
      u32x4 bv;
      bv[0] = pk2(a0.x * sc, a0.y * sc); bv[1] = pk2(a0.z * sc, a0.w * sc);
      bv[2] = pk2(a1.x * sc, a1.y * sc); bv[3] = pk2(a1.z * sc, a1.w * sc);
      fih[kt][g] = __builtin_bit_cast(s16x8, bv);
      const float4* p2 = (const float4*)(W_hh + n * D_ + kt * 32 + lg * 8);
      float4 c0v = p2[0], c1v = p2[1];
      u32x4 cv;
      cv[0] = pk2(c0v.x * sc, c0v.y * sc); cv[1] = pk2(c0v.z * sc, c0v.w * sc);
      cv[2] = pk2(c1v.x * sc, c1v.y * sc); cv[3] = pk2(c1v.z * sc, c1v.w * sc);
      fhh[kt][g] = __builtin_bit_cast(s16x8, cv);
    }
  }
  // h LDS addresses (r7-proven swizzle)
  unsigned rd_[4];
  #pragma unroll
  for (int kt = 0; kt < 4; kt++)
    rd_[kt] = (unsigned)(hr * 256 + (((kt << 2) + lg) ^ ((hr & 1) << 2)) * 16);
  unsigned wr_ = (unsigned)(lg * 256 + ((d >> 3) ^ ((lg & 1) << 2)) * 16 + (d & 7) * 2);
  // G1 float4 idx: write m=lg*4+r ; read m=TS*4+lg (wave-local)
  int gw0 = lg * 512 + d;
  int gr0 = lg * 128 + d;

  float* op = out_e + (size_t)(row0 + lg) * T_ * D_ + d;
  float cst = 0.f;
  if (tid < 128) ((uint2*)hl)[tid] = make_uint2(0u, 0u);   // zero h buf0 (1 KB)

  // fih A stream (r7-identical): wx[4g + (l15>>2)][row0 + (l15&3)][k-slice lg*8]
  const unsigned short* wp = wxb + ((size_t)(l15 >> 2) * B_ + row0 + (l15 & 3)) * D_ + lg * 8;
  const size_t GSTRIDE = (size_t)4 * B_ * D_;               // 4 timesteps
  s16x8 AF[4];
  #pragma unroll
  for (int kt = 0; kt < 4; kt++) AF[kt] = *(const s16x8*)(wp + kt * 32);
  wp += GSTRIDE;
  __syncthreads();

  // ---- batch-fih: 16 MFMA -> f32 G1 (scaled) for 4 steps -> LDS (wave-local) ----
#define FIH_BATCH() do {                                                            \
    f32x4 p0 = {biasS[0], biasS[0], biasS[0], biasS[0]};                            \
    f32x4 p1 = {biasS[1], biasS[1], biasS[1], biasS[1]};                            \
    f32x4 p2 = {biasS[2], biasS[2], biasS[2], biasS[2]};                            \
    f32x4 p3 = {biasS[3], biasS[3], biasS[3], biasS[3]};                            \
    _Pragma("unroll")                                                               \
    for (int kt = 0; kt < 4; kt++){                                                 \
      p0 = __builtin_amdgcn_mfma_f32_16x16x32_bf16(AF[kt], fih[kt][0], p0,0,0,0);   \
      p1 = __builtin_amdgcn_mfma_f32_16x16x32_bf16(AF[kt], fih[kt][1], p1,0,0,0);   \
      p2 = __builtin_amdgcn_mfma_f32_16x16x32_bf16(AF[kt], fih[kt][2], p2,0,0,0);   \
      p3 = __builtin_amdgcn_mfma_f32_16x16x32_bf16(AF[kt], fih[kt][3], p3,0,0,0);   \
    }                                                                               \
    _Pragma("unroll")                                                               \
    for (int r = 0; r < 4; r++)                                                     \
      g1l[gw0 + r * 128] = make_float4(p0[r], p1[r], p2[r], p3[r]);                 \
  } while (0)

  // ---- one recurrence step (TS compile-time 0..3; h buf parity = TS&1) ----
#define STEP(TS) do {                                                               \
    s16x8 aa[4];                                                                    \
    _Pragma("unroll")                                                               \
    for (int kt = 0; kt < 4; kt++)                                                  \
      aa[kt] = *(const s16x8*)(hl + rd_[kt] + ((TS) & 1) * 1024);                   \
    f32x4 a0 = {0.f,0.f,0.f,0.f}, a1 = a0, a2 = a0, a3 = a0;                        \
    _Pragma("unroll")                                                               \
    for (int kt = 0; kt < 4; kt++){                                                 \
      a0 = __builtin_amdgcn_mfma_f32_16x16x32_bf16(aa[kt], fhh[kt][0], a0,0,0,0);   \
      a1 = __builtin_amdgcn_mfma_f32_16x16x32_bf16(aa[kt], fhh[kt][1], a1,0,0,0);   \
      a2 = __builtin_amdgcn_mfma_f32_16x16x32_bf16(aa[kt], fhh[kt][2], a2,0,0,0);   \
      a3 = __builtin_amdgcn_mfma_f32_16x16x32_bf16(aa[kt], fhh[kt][3], a3,0,0,0);   \
    }                                                                               \
    float4 q = g1l[gr0 + (TS) * 512];                                               \
    float gi = q.x + a0[0], gf = q.y + a1[0];                                       \
    float gg = q.z + a2[0], go = q.w + a3[0];                                       \
    float cn = fmaf(sg(gf), cst, sg(gi) * tg(gg));                                  \
    float hn = sg(go) * tc_(cn); cst = cn;                                          \
    *op = hn; op += D_;                                                             \
    *(unsigned short*)(hl + wr_ + (1 - ((TS) & 1)) * 1024) = bf1(hn);               \
    __syncthreads();                                                                \
  } while (0)

  for (int g = 0; g < 63; g++){
    FIH_BATCH();
    #pragma unroll
    for (int kt = 0; kt < 4; kt++) AF[kt] = *(const s16x8*)(wp + kt * 32);
    wp += GSTRIDE;          // g=62 loads group 63 (t up to 255: zeroed pad slot)
    STEP(0); STEP(1); STEP(2); STEP(3);
  }
  // epilogue group: t = 252,253,254 (G1[ts=3] from zero pad, never read)
  FIH_BATCH();
  STEP(0); STEP(1); STEP(2);
#undef FIH_BATCH
#undef STEP
}

extern "C" void kernel_launch(void* const* d_in, const int* in_sizes, int n_in,
                              void* d_out, int out_size, void* d_ws, size_t ws_size,
                              hipStream_t stream) {
  (void)in_sizes; (void)n_in; (void)out_size;
  const float* x    = (const float*)d_in[0];
  const float* Wa   = (const float*)d_in[1];
  // d_in[2] = ba : dead (softmax shift invariance); Wh/Wc parts of Wa also dead
  const float* W_ih = (const float*)d_in[3];
  const float* W_hh = (const float*)d_in[4];
  const float* b_ih = (const float*)d_in[5];
  const float* b_hh = (const float*)d_in[6];
  float* out_w = (float*)d_out;
  float* out_e = out_w + (size_t)B_ * T_ * D_;
  unsigned short* wxb = (unsigned short*)d_ws;   // [t][b][d] bf16; T+1 slots
  size_t need = (size_t)(T_ + 1) * B_ * D_ * 2;  // 67.1 MB (t=255 pad, zeroed by k_attn)
  if (ws_size < need) return;

  k_attn<<<B_, 512, 130560, stream>>>(x, Wa, out_w, (uint2*)wxb);
  k_rnn <<<256, 512, 0, stream>>>(W_ih, W_hh, b_ih, b_hh, wxb, out_e);
}